// Round 2
// baseline (976.395 us; speedup 1.0000x reference)
//
#include <hip/hip_runtime.h>
#include <cstdint>
#include <cstddef>

#define TPB 256

// ---------------- preprocessing ----------------

__global__ void init_k(float* __restrict__ deg, int* __restrict__ cnt, int n) {
  int i = blockIdx.x * TPB + threadIdx.x;
  if (i < n) { deg[i] = 1.0f; cnt[i] = 0; }  // deg starts at 1.0 (self loop)
}

__global__ void edges_k(const int* __restrict__ ei, const float* __restrict__ w,
                        float* __restrict__ deg, int* __restrict__ cnt, int E) {
  int e = blockIdx.x * TPB + threadIdx.x;
  if (e >= E) return;
  int d = ei[E + e];
  atomicAdd(&deg[d], w[e]);
  atomicAdd(&cnt[d], 1);
}

__global__ void dinv_k(const float* __restrict__ deg, float* __restrict__ dinv, int n) {
  int i = blockIdx.x * TPB + threadIdx.x;
  if (i < n) { float dg = deg[i]; dinv[i] = dg > 0.f ? rsqrtf(dg) : 0.f; }
}

__global__ void scan_a(const int* __restrict__ cnt, int* __restrict__ rp,
                       int* __restrict__ bsum, int n) {
  __shared__ int s[TPB];
  int i = blockIdx.x * TPB + threadIdx.x;
  int v = (i < n) ? cnt[i] : 0;
  s[threadIdx.x] = v;
  __syncthreads();
  #pragma unroll
  for (int off = 1; off < TPB; off <<= 1) {
    int t = (threadIdx.x >= off) ? s[threadIdx.x - off] : 0;
    __syncthreads();
    s[threadIdx.x] += t;
    __syncthreads();
  }
  if (i < n) rp[i] = s[threadIdx.x] - v;            // exclusive within block
  if (threadIdx.x == TPB - 1) bsum[blockIdx.x] = s[TPB - 1];
}

__global__ void scan_b(int* __restrict__ bsum, int nb) {
  __shared__ int s[512];
  int v = (threadIdx.x < nb) ? bsum[threadIdx.x] : 0;
  s[threadIdx.x] = v;
  __syncthreads();
  #pragma unroll
  for (int off = 1; off < 512; off <<= 1) {
    int t = (threadIdx.x >= off) ? s[threadIdx.x - off] : 0;
    __syncthreads();
    s[threadIdx.x] += t;
    __syncthreads();
  }
  if (threadIdx.x < nb) bsum[threadIdx.x] = s[threadIdx.x] - v;  // exclusive block offsets
}

__global__ void scan_c(int* __restrict__ rp, const int* __restrict__ bsum,
                       int* __restrict__ cursor, int n, int etot) {
  int i = blockIdx.x * TPB + threadIdx.x;
  if (i < n) { rp[i] += bsum[blockIdx.x]; cursor[i] = 0; }
  if (blockIdx.x == 0 && threadIdx.x == 0) rp[n] = etot;
}

__global__ void fill_k(const int* __restrict__ ei, const float* __restrict__ w,
                       const float* __restrict__ dinv, const int* __restrict__ rp,
                       int* __restrict__ cursor,
                       int* __restrict__ ecol, float* __restrict__ enorm, int E) {
  int e = blockIdx.x * TPB + threadIdx.x;
  if (e >= E) return;
  int s = ei[e];
  int d = ei[E + e];
  int pos = rp[d] + atomicAdd(&cursor[d], 1);
  ecol[pos]  = s;
  enorm[pos] = dinv[s] * w[e] * dinv[d];
}

// ---------------- GEMM: H = act(X) @ W  (K=128 fixed) ----------------
// Block: 256 threads. W staged in LDS in two K=64 halves (<=48KB total LDS),
// X tile staged once, 4 rows x 4 cols register blocking per thread.

template<int COUT, bool RELU>
__global__ __launch_bounds__(256) void gemm_k(const float* __restrict__ X,
                                              const float* __restrict__ W,
                                              float* __restrict__ H, int n) {
  constexpr int CG   = COUT / 4;     // column groups (32 or 16)
  constexpr int RG   = 256 / CG;     // row groups   (8 or 16)
  constexpr int ROWS = RG * 4;       // rows/block   (32 or 64)
  __shared__ __align__(16) float Ws[64 * COUT];    // 32KB (128) / 16KB (64)
  __shared__ __align__(16) float Xs[ROWS * 128];   // 16KB (128) / 32KB (64)

  const int tid = threadIdx.x;
  const int r0  = blockIdx.x * ROWS;

  // stage X tile once (apply ReLU on load if requested)
  const int nrow = min(ROWS, n - r0);
  const float4* X4  = (const float4*)(X + (size_t)r0 * 128);
  float4*       Xs4 = (float4*)Xs;
  for (int i = tid; i < nrow * 32; i += 256) {
    float4 v = X4[i];
    if (RELU) {
      v.x = fmaxf(v.x, 0.f); v.y = fmaxf(v.y, 0.f);
      v.z = fmaxf(v.z, 0.f); v.w = fmaxf(v.w, 0.f);
    }
    Xs4[i] = v;
  }

  const int cg   = tid % CG;
  const int rg   = tid / CG;
  const int col0 = cg * 4;
  const int rb   = rg * 4;

  float4 acc[4];
  #pragma unroll
  for (int r = 0; r < 4; r++) acc[r] = make_float4(0.f, 0.f, 0.f, 0.f);

  for (int kb = 0; kb < 128; kb += 64) {
    __syncthreads();   // protects Ws reuse (and X staging on first pass)
    // stage W half (coalesced float4)
    const float4* W4  = (const float4*)(W + (size_t)kb * COUT);
    float4*       Ws4 = (float4*)Ws;
    #pragma unroll
    for (int i = tid; i < 64 * COUT / 4; i += 256) Ws4[i] = W4[i];
    __syncthreads();

    #pragma unroll
    for (int k = 0; k < 64; k += 4) {
      float4 w0 = *(const float4*)&Ws[(k + 0) * COUT + col0];
      float4 w1 = *(const float4*)&Ws[(k + 1) * COUT + col0];
      float4 w2 = *(const float4*)&Ws[(k + 2) * COUT + col0];
      float4 w3 = *(const float4*)&Ws[(k + 3) * COUT + col0];
      #pragma unroll
      for (int r = 0; r < 4; r++) {
        float4 xv = *(const float4*)&Xs[(rb + r) * 128 + kb + k];
        acc[r].x += xv.x * w0.x + xv.y * w1.x + xv.z * w2.x + xv.w * w3.x;
        acc[r].y += xv.x * w0.y + xv.y * w1.y + xv.z * w2.y + xv.w * w3.y;
        acc[r].z += xv.x * w0.z + xv.y * w1.z + xv.z * w2.z + xv.w * w3.z;
        acc[r].w += xv.x * w0.w + xv.y * w1.w + xv.z * w2.w + xv.w * w3.w;
      }
    }
  }

  #pragma unroll
  for (int r = 0; r < 4; r++) {
    int row = r0 + rb + r;
    if (row < n) *(float4*)&H[(size_t)row * COUT + col0] = acc[r];
  }
}

// ---------------- aggregation: one wave per node, CSR gather ----------------
// out[j][c] = b[c] + dinv[j]^2 * h[j][c] + sum_e norm_e * h[col_e][c]

__global__ __launch_bounds__(256) void agg128(const float* __restrict__ H,
                                              const int* __restrict__ rp,
                                              const int* __restrict__ ecol,
                                              const float* __restrict__ enorm,
                                              const float* __restrict__ dinv,
                                              const float* __restrict__ bias,
                                              float* __restrict__ OUT, int n) {
  int wid  = (blockIdx.x * 256 + threadIdx.x) >> 6;
  int lane = threadIdx.x & 63;
  if (wid >= n) return;
  float di = dinv[wid];
  float w0 = di * di;
  float2 hv = ((const float2*)(H + (size_t)wid * 128))[lane];
  float2 bv = ((const float2*)bias)[lane];
  float ax = bv.x + w0 * hv.x;
  float ay = bv.y + w0 * hv.y;
  int e1 = rp[wid + 1];
  for (int e = rp[wid]; e < e1; e++) {
    int   s = ecol[e];
    float w = enorm[e];
    float2 hs = ((const float2*)(H + (size_t)s * 128))[lane];
    ax += w * hs.x;
    ay += w * hs.y;
  }
  ((float2*)(OUT + (size_t)wid * 128))[lane] = make_float2(ax, ay);
}

__global__ __launch_bounds__(256) void agg64(const float* __restrict__ H,
                                             const int* __restrict__ rp,
                                             const int* __restrict__ ecol,
                                             const float* __restrict__ enorm,
                                             const float* __restrict__ dinv,
                                             const float* __restrict__ bias,
                                             float* __restrict__ OUT, int n) {
  int wid  = (blockIdx.x * 256 + threadIdx.x) >> 6;
  int lane = threadIdx.x & 63;
  if (wid >= n) return;
  float di = dinv[wid];
  float w0 = di * di;
  float acc = bias[lane] + w0 * H[(size_t)wid * 64 + lane];
  int e1 = rp[wid + 1];
  for (int e = rp[wid]; e < e1; e++) {
    int   s = ecol[e];
    float w = enorm[e];
    acc += w * H[(size_t)s * 64 + lane];
  }
  OUT[(size_t)wid * 64 + lane] = acc;
}

// ---------------- launch ----------------

extern "C" void kernel_launch(void* const* d_in, const int* in_sizes, int n_in,
                              void* d_out, int out_size, void* d_ws, size_t ws_size,
                              hipStream_t stream) {
  const float* x  = (const float*)d_in[0];
  const int*   ei = (const int*)d_in[1];    // int64 in reference -> int32 on device
  const float* ew = (const float*)d_in[2];
  const float* W1 = (const float*)d_in[3];
  const float* b1 = (const float*)d_in[4];
  const float* W2 = (const float*)d_in[5];
  const float* b2 = (const float*)d_in[6];
  const float* W3 = (const float*)d_in[7];
  const float* b3 = (const float*)d_in[8];

  const int N = in_sizes[0] / 128;
  const int E = in_sizes[2];

  char* p = (char*)d_ws;
  auto carve = [&](size_t bytes) -> void* {
    void* r = (void*)p;
    p += (bytes + 255) & ~(size_t)255;
    return r;
  };
  float* deg    = (float*)carve((size_t)N * 4);
  float* dinv   = (float*)carve((size_t)N * 4);
  int*   cnt    = (int*)  carve((size_t)N * 4);   // reused as cursor after scan
  int*   rp     = (int*)  carve((size_t)(N + 1) * 4);
  int*   bsum   = (int*)  carve(512 * 4);
  int*   ecol   = (int*)  carve((size_t)E * 4);
  float* enorm  = (float*)carve((size_t)E * 4);
  float* hbuf   = (float*)carve((size_t)N * 128 * 4);
  float* abuf   = (float*)carve((size_t)N * 128 * 4);

  const int NB = (N + TPB - 1) / TPB;
  const int EB = (E + TPB - 1) / TPB;

  // graph preprocessing (once per call; reused by all 3 layers)
  init_k<<<NB, TPB, 0, stream>>>(deg, cnt, N);
  edges_k<<<EB, TPB, 0, stream>>>(ei, ew, deg, cnt, E);
  dinv_k<<<NB, TPB, 0, stream>>>(deg, dinv, N);
  scan_a<<<NB, TPB, 0, stream>>>(cnt, rp, bsum, N);
  scan_b<<<1, 512, 0, stream>>>(bsum, NB);
  scan_c<<<NB, TPB, 0, stream>>>(rp, bsum, cnt, N, E);   // also zeroes cursor(=cnt)
  fill_k<<<EB, TPB, 0, stream>>>(ei, ew, dinv, rp, cnt, ecol, enorm, E);

  const int aggBlocks = (N + 3) / 4;   // one 64-lane wave per node, 4 waves/block

  // layer 1: h = x @ W1 ; agg + b1   (ReLU fused into next gemm's load)
  gemm_k<128, false><<<(N + 31) / 32, 256, 0, stream>>>(x, W1, hbuf, N);
  agg128<<<aggBlocks, 256, 0, stream>>>(hbuf, rp, ecol, enorm, dinv, b1, abuf, N);

  // layer 2: h = relu(a1) @ W2 ; agg + b2
  gemm_k<128, true><<<(N + 31) / 32, 256, 0, stream>>>(abuf, W2, hbuf, N);
  agg128<<<aggBlocks, 256, 0, stream>>>(hbuf, rp, ecol, enorm, dinv, b2, abuf, N);

  // layer 3: h = relu(a2) @ W3 ; agg + b3 -> d_out
  gemm_k<64, true><<<(N + 63) / 64, 256, 0, stream>>>(abuf, W3, hbuf, N);
  agg64<<<aggBlocks, 256, 0, stream>>>(hbuf, rp, ecol, enorm, dinv, b3, (float*)d_out, N);
}

// Round 4
// 581.896 us; speedup vs baseline: 1.6780x; 1.6780x over previous
//
#include <hip/hip_runtime.h>
#include <cstdint>
#include <cstddef>

#define TPB 256

// fp32 -> bf16 (round to nearest even), as raw ushort
__device__ __forceinline__ unsigned short f2bf(float f) {
  unsigned u = __float_as_uint(f);
  u += 0x7fffu + ((u >> 16) & 1u);
  return (unsigned short)(u >> 16);
}
__device__ __forceinline__ float bf_lo(unsigned u) { return __uint_as_float(u << 16); }
__device__ __forceinline__ float bf_hi(unsigned u) { return __uint_as_float(u & 0xffff0000u); }

// ---------------- preprocessing ----------------

__global__ void init_k(float* __restrict__ deg, int* __restrict__ cnt, int n) {
  int i = blockIdx.x * TPB + threadIdx.x;
  if (i < n) { deg[i] = 1.0f; cnt[i] = 0; }  // deg starts at 1.0 (self loop)
}

__global__ void edges_k(const int* __restrict__ ei, const float* __restrict__ w,
                        float* __restrict__ deg, int* __restrict__ cnt, int E) {
  int e = blockIdx.x * TPB + threadIdx.x;
  if (e >= E) return;
  int d = ei[E + e];
  atomicAdd(&deg[d], w[e]);
  atomicAdd(&cnt[d], 1);
}

__global__ void dinv_k(const float* __restrict__ deg, float* __restrict__ dinv, int n) {
  int i = blockIdx.x * TPB + threadIdx.x;
  if (i < n) { float dg = deg[i]; dinv[i] = dg > 0.f ? rsqrtf(dg) : 0.f; }
}

__global__ void scan_a(const int* __restrict__ cnt, int* __restrict__ rp,
                       int* __restrict__ bsum, int n) {
  __shared__ int s[TPB];
  int i = blockIdx.x * TPB + threadIdx.x;
  int v = (i < n) ? cnt[i] : 0;
  s[threadIdx.x] = v;
  __syncthreads();
  #pragma unroll
  for (int off = 1; off < TPB; off <<= 1) {
    int t = (threadIdx.x >= off) ? s[threadIdx.x - off] : 0;
    __syncthreads();
    s[threadIdx.x] += t;
    __syncthreads();
  }
  if (i < n) rp[i] = s[threadIdx.x] - v;            // exclusive within block
  if (threadIdx.x == TPB - 1) bsum[blockIdx.x] = s[TPB - 1];
}

__global__ void scan_b(int* __restrict__ bsum, int nb) {
  __shared__ int s[512];
  int v = (threadIdx.x < nb) ? bsum[threadIdx.x] : 0;
  s[threadIdx.x] = v;
  __syncthreads();
  #pragma unroll
  for (int off = 1; off < 512; off <<= 1) {
    int t = (threadIdx.x >= off) ? s[threadIdx.x - off] : 0;
    __syncthreads();
    s[threadIdx.x] += t;
    __syncthreads();
  }
  if (threadIdx.x < nb) bsum[threadIdx.x] = s[threadIdx.x] - v;  // exclusive block offsets
}

__global__ void scan_c(int* __restrict__ rp, const int* __restrict__ bsum,
                       int* __restrict__ cursor, int n, int etot) {
  int i = blockIdx.x * TPB + threadIdx.x;
  if (i < n) { rp[i] += bsum[blockIdx.x]; cursor[i] = 0; }
  if (blockIdx.x == 0 && threadIdx.x == 0) rp[n] = etot;
}

// epack[pos] = (src, norm) interleaved -> single 8B load per edge in agg
__global__ void fill_k(const int* __restrict__ ei, const float* __restrict__ w,
                       const float* __restrict__ dinv, const int* __restrict__ rp,
                       int* __restrict__ cursor, int2* __restrict__ epk, int E) {
  int e = blockIdx.x * TPB + threadIdx.x;
  if (e >= E) return;
  int s = ei[e];
  int d = ei[E + e];
  int pos = rp[d] + atomicAdd(&cursor[d], 1);
  float nrm = dinv[s] * w[e] * dinv[d];
  epk[pos] = make_int2(s, __float_as_int(nrm));
}

// ---------------- GEMM: H = act(X) @ W  (K=128 fixed), bf16 output ----------------

template<int COUT, bool RELU>
__global__ __launch_bounds__(256) void gemm_k(const float* __restrict__ X,
                                              const float* __restrict__ W,
                                              unsigned short* __restrict__ H, int n) {
  constexpr int CG   = COUT / 4;     // column groups (32 or 16)
  constexpr int RG   = 256 / CG;     // row groups   (8 or 16)
  constexpr int ROWS = RG * 4;       // rows/block   (32 or 64)
  __shared__ __align__(16) float Ws[64 * COUT];    // 32KB (128) / 16KB (64)
  __shared__ __align__(16) float Xs[ROWS * 128];   // 16KB (128) / 32KB (64)

  const int tid = threadIdx.x;
  const int r0  = blockIdx.x * ROWS;

  // stage X tile once (apply ReLU on load if requested)
  const int nrow = min(ROWS, n - r0);
  const float4* X4  = (const float4*)(X + (size_t)r0 * 128);
  float4*       Xs4 = (float4*)Xs;
  for (int i = tid; i < nrow * 32; i += 256) {
    float4 v = X4[i];
    if (RELU) {
      v.x = fmaxf(v.x, 0.f); v.y = fmaxf(v.y, 0.f);
      v.z = fmaxf(v.z, 0.f); v.w = fmaxf(v.w, 0.f);
    }
    Xs4[i] = v;
  }

  const int cg   = tid % CG;
  const int rg   = tid / CG;
  const int col0 = cg * 4;
  const int rb   = rg * 4;

  float4 acc[4];
  #pragma unroll
  for (int r = 0; r < 4; r++) acc[r] = make_float4(0.f, 0.f, 0.f, 0.f);

  for (int kb = 0; kb < 128; kb += 64) {
    __syncthreads();   // protects Ws reuse (and X staging on first pass)
    const float4* W4  = (const float4*)(W + (size_t)kb * COUT);
    float4*       Ws4 = (float4*)Ws;
    #pragma unroll
    for (int i = tid; i < 64 * COUT / 4; i += 256) Ws4[i] = W4[i];
    __syncthreads();

    #pragma unroll
    for (int k = 0; k < 64; k += 4) {
      float4 w0 = *(const float4*)&Ws[(k + 0) * COUT + col0];
      float4 w1 = *(const float4*)&Ws[(k + 1) * COUT + col0];
      float4 w2 = *(const float4*)&Ws[(k + 2) * COUT + col0];
      float4 w3 = *(const float4*)&Ws[(k + 3) * COUT + col0];
      #pragma unroll
      for (int r = 0; r < 4; r++) {
        float4 xv = *(const float4*)&Xs[(rb + r) * 128 + kb + k];
        acc[r].x += xv.x * w0.x + xv.y * w1.x + xv.z * w2.x + xv.w * w3.x;
        acc[r].y += xv.x * w0.y + xv.y * w1.y + xv.z * w2.y + xv.w * w3.y;
        acc[r].z += xv.x * w0.z + xv.y * w1.z + xv.z * w2.z + xv.w * w3.z;
        acc[r].w += xv.x * w0.w + xv.y * w1.w + xv.z * w2.w + xv.w * w3.w;
      }
    }
  }

  #pragma unroll
  for (int r = 0; r < 4; r++) {
    int row = r0 + rb + r;
    if (row < n) {
      ushort4 o;
      o.x = f2bf(acc[r].x);
      o.y = f2bf(acc[r].y);
      o.z = f2bf(acc[r].z);
      o.w = f2bf(acc[r].w);
      *(ushort4*)&H[(size_t)row * COUT + col0] = o;
    }
  }
}

// ---------------- aggregation: one wave per node, CSR gather (bf16 table) ----------
// out[j][c] = b[c] + dinv[j]^2 * h[j][c] + sum_e norm_e * h[col_e][c]

__global__ __launch_bounds__(256) void agg128(const unsigned short* __restrict__ H,
                                              const int* __restrict__ rp,
                                              const int2* __restrict__ epk,
                                              const float* __restrict__ dinv,
                                              const float* __restrict__ bias,
                                              float* __restrict__ OUT, int n) {
  int wid  = __builtin_amdgcn_readfirstlane(blockIdx.x * 4 + (threadIdx.x >> 6));
  int lane = threadIdx.x & 63;
  if (wid >= n) return;
  float di = dinv[wid];
  float w0 = di * di;
  unsigned hv = ((const unsigned*)(H + (size_t)wid * 128))[lane];
  float2 bv = ((const float2*)bias)[lane];
  float ax = bv.x + w0 * bf_lo(hv);
  float ay = bv.y + w0 * bf_hi(hv);
  int e  = rp[wid];
  int e1 = rp[wid + 1];
  for (; e + 3 < e1; e += 4) {
    int2 p0 = epk[e], p1 = epk[e + 1], p2 = epk[e + 2], p3 = epk[e + 3];
    unsigned h0 = ((const unsigned*)(H + (size_t)p0.x * 128))[lane];
    unsigned h1 = ((const unsigned*)(H + (size_t)p1.x * 128))[lane];
    unsigned h2 = ((const unsigned*)(H + (size_t)p2.x * 128))[lane];
    unsigned h3 = ((const unsigned*)(H + (size_t)p3.x * 128))[lane];
    float n0 = __int_as_float(p0.y), n1 = __int_as_float(p1.y);
    float n2 = __int_as_float(p2.y), n3 = __int_as_float(p3.y);
    ax += n0 * bf_lo(h0); ay += n0 * bf_hi(h0);
    ax += n1 * bf_lo(h1); ay += n1 * bf_hi(h1);
    ax += n2 * bf_lo(h2); ay += n2 * bf_hi(h2);
    ax += n3 * bf_lo(h3); ay += n3 * bf_hi(h3);
  }
  for (; e < e1; e++) {
    int2 p = epk[e];
    unsigned h = ((const unsigned*)(H + (size_t)p.x * 128))[lane];
    float nw = __int_as_float(p.y);
    ax += nw * bf_lo(h); ay += nw * bf_hi(h);
  }
  ((float2*)(OUT + (size_t)wid * 128))[lane] = make_float2(ax, ay);
}

__global__ __launch_bounds__(256) void agg64(const unsigned short* __restrict__ H,
                                             const int* __restrict__ rp,
                                             const int2* __restrict__ epk,
                                             const float* __restrict__ dinv,
                                             const float* __restrict__ bias,
                                             float* __restrict__ OUT, int n) {
  int wid  = __builtin_amdgcn_readfirstlane(blockIdx.x * 4 + (threadIdx.x >> 6));
  int lane = threadIdx.x & 63;
  if (wid >= n) return;
  float di = dinv[wid];
  float w0 = di * di;
  float hv = __uint_as_float(((unsigned)H[(size_t)wid * 64 + lane]) << 16);
  float acc = bias[lane] + w0 * hv;
  int e  = rp[wid];
  int e1 = rp[wid + 1];
  for (; e + 3 < e1; e += 4) {
    int2 p0 = epk[e], p1 = epk[e + 1], p2 = epk[e + 2], p3 = epk[e + 3];
    float h0 = __uint_as_float(((unsigned)H[(size_t)p0.x * 64 + lane]) << 16);
    float h1 = __uint_as_float(((unsigned)H[(size_t)p1.x * 64 + lane]) << 16);
    float h2 = __uint_as_float(((unsigned)H[(size_t)p2.x * 64 + lane]) << 16);
    float h3 = __uint_as_float(((unsigned)H[(size_t)p3.x * 64 + lane]) << 16);
    acc += __int_as_float(p0.y) * h0;
    acc += __int_as_float(p1.y) * h1;
    acc += __int_as_float(p2.y) * h2;
    acc += __int_as_float(p3.y) * h3;
  }
  for (; e < e1; e++) {
    int2 p = epk[e];
    float h = __uint_as_float(((unsigned)H[(size_t)p.x * 64 + lane]) << 16);
    acc += __int_as_float(p.y) * h;
  }
  OUT[(size_t)wid * 64 + lane] = acc;
}

// ---------------- launch ----------------

extern "C" void kernel_launch(void* const* d_in, const int* in_sizes, int n_in,
                              void* d_out, int out_size, void* d_ws, size_t ws_size,
                              hipStream_t stream) {
  const float* x  = (const float*)d_in[0];
  const int*   ei = (const int*)d_in[1];    // int64 in reference -> int32 on device
  const float* ew = (const float*)d_in[2];
  const float* W1 = (const float*)d_in[3];
  const float* b1 = (const float*)d_in[4];
  const float* W2 = (const float*)d_in[5];
  const float* b2 = (const float*)d_in[6];
  const float* W3 = (const float*)d_in[7];
  const float* b3 = (const float*)d_in[8];

  const int N = in_sizes[0] / 128;
  const int E = in_sizes[2];

  char* p = (char*)d_ws;
  auto carve = [&](size_t bytes) -> void* {
    void* r = (void*)p;
    p += (bytes + 255) & ~(size_t)255;
    return r;
  };
  float* deg    = (float*)carve((size_t)N * 4);
  float* dinv   = (float*)carve((size_t)N * 4);
  int*   cnt    = (int*)  carve((size_t)N * 4);   // reused as cursor after scan
  int*   rp     = (int*)  carve((size_t)(N + 1) * 4);
  int*   bsum   = (int*)  carve(512 * 4);
  int2*  epk    = (int2*) carve((size_t)E * 8);
  unsigned short* hbuf = (unsigned short*)carve((size_t)N * 128 * 2);  // bf16 table
  float* abuf   = (float*)carve((size_t)N * 128 * 4);

  const int NB = (N + TPB - 1) / TPB;
  const int EB = (E + TPB - 1) / TPB;

  // graph preprocessing (once per call; reused by all 3 layers)
  init_k<<<NB, TPB, 0, stream>>>(deg, cnt, N);
  edges_k<<<EB, TPB, 0, stream>>>(ei, ew, deg, cnt, E);
  dinv_k<<<NB, TPB, 0, stream>>>(deg, dinv, N);
  scan_a<<<NB, TPB, 0, stream>>>(cnt, rp, bsum, N);
  scan_b<<<1, 512, 0, stream>>>(bsum, NB);
  scan_c<<<NB, TPB, 0, stream>>>(rp, bsum, cnt, N, E);   // also zeroes cursor(=cnt)
  fill_k<<<EB, TPB, 0, stream>>>(ei, ew, dinv, rp, cnt, epk, E);

  const int aggBlocks = (N + 3) / 4;   // one 64-lane wave per node, 4 waves/block

  // layer 1: h = x @ W1 (bf16) ; agg + b1 -> abuf fp32
  gemm_k<128, false><<<(N + 31) / 32, 256, 0, stream>>>(x, W1, hbuf, N);
  agg128<<<aggBlocks, 256, 0, stream>>>(hbuf, rp, epk, dinv, b1, abuf, N);

  // layer 2: h = relu(a1) @ W2 (bf16) ; agg + b2 -> abuf fp32
  gemm_k<128, true><<<(N + 31) / 32, 256, 0, stream>>>(abuf, W2, hbuf, N);
  agg128<<<aggBlocks, 256, 0, stream>>>(hbuf, rp, epk, dinv, b2, abuf, N);

  // layer 3: h = relu(a2) @ W3 (bf16) ; agg + b3 -> d_out fp32
  gemm_k<64, true><<<(N + 63) / 64, 256, 0, stream>>>(abuf, W3, hbuf, N);
  agg64<<<aggBlocks, 256, 0, stream>>>(hbuf, rp, epk, dinv, b3, (float*)d_out, N);
}

// Round 6
// 462.848 us; speedup vs baseline: 2.1095x; 1.2572x over previous
//
#include <hip/hip_runtime.h>
#include <cstdint>
#include <cstddef>

#define TPB 256

// fp32 -> bf16 (round to nearest even), as raw ushort
__device__ __forceinline__ unsigned short f2bf(float f) {
  unsigned u = __float_as_uint(f);
  u += 0x7fffu + ((u >> 16) & 1u);
  return (unsigned short)(u >> 16);
}
__device__ __forceinline__ float bf_lo(unsigned u) { return __uint_as_float(u << 16); }
__device__ __forceinline__ float bf_hi(unsigned u) { return __uint_as_float(u & 0xffff0000u); }

#define FIXP 262144.0f   // 2^18 fixed-point scale for weighted degree
#define LOWMASK 0xFFFFFFFFFFULL

// ---------------- preprocessing ----------------

__global__ void init_k(unsigned long long* __restrict__ pk, int n) {
  int i = blockIdx.x * TPB + threadIdx.x;
  if (i < n) pk[i] = 0ULL;
}

// ONE packed atomic per edge: count in high 24 bits, fixed-point weighted degree in
// low 40 bits. Returned old count field = this edge's slot within its CSR row.
__global__ void edges_k(const int* __restrict__ ei, const float* __restrict__ w,
                        unsigned long long* __restrict__ pk, int* __restrict__ pir, int E) {
  int e = blockIdx.x * TPB + threadIdx.x;
  if (e >= E) return;
  int d = ei[E + e];
  unsigned long long v = (1ULL << 40) | (unsigned long long)(w[e] * FIXP + 0.5f);
  unsigned long long old = atomicAdd(&pk[d], v);
  pir[e] = (int)(old >> 40);
}

__global__ void unpack_k(const unsigned long long* __restrict__ pk,
                         float* __restrict__ dinv, int* __restrict__ cnt, int n) {
  int i = blockIdx.x * TPB + threadIdx.x;
  if (i >= n) return;
  unsigned long long p = pk[i];
  float deg = 1.0f + (float)(p & LOWMASK) * (1.0f / FIXP);   // self-loop weight 1 => deg >= 1
  dinv[i] = rsqrtf(deg);
  cnt[i]  = (int)(p >> 40);
}

__global__ void scan_a(const int* __restrict__ cnt, int* __restrict__ rp,
                       int* __restrict__ bsum, int n) {
  __shared__ int s[TPB];
  int i = blockIdx.x * TPB + threadIdx.x;
  int v = (i < n) ? cnt[i] : 0;
  s[threadIdx.x] = v;
  __syncthreads();
  #pragma unroll
  for (int off = 1; off < TPB; off <<= 1) {
    int t = (threadIdx.x >= off) ? s[threadIdx.x - off] : 0;
    __syncthreads();
    s[threadIdx.x] += t;
    __syncthreads();
  }
  if (i < n) rp[i] = s[threadIdx.x] - v;            // exclusive within block
  if (threadIdx.x == TPB - 1) bsum[blockIdx.x] = s[TPB - 1];
}

__global__ void scan_b(int* __restrict__ bsum, int nb) {
  __shared__ int s[512];
  int v = (threadIdx.x < nb) ? bsum[threadIdx.x] : 0;
  s[threadIdx.x] = v;
  __syncthreads();
  #pragma unroll
  for (int off = 1; off < 512; off <<= 1) {
    int t = (threadIdx.x >= off) ? s[threadIdx.x - off] : 0;
    __syncthreads();
    s[threadIdx.x] += t;
    __syncthreads();
  }
  if (threadIdx.x < nb) bsum[threadIdx.x] = s[threadIdx.x] - v;  // exclusive block offsets
}

__global__ void scan_c(int* __restrict__ rp, const int* __restrict__ bsum, int n, int etot) {
  int i = blockIdx.x * TPB + threadIdx.x;
  if (i < n) rp[i] += bsum[blockIdx.x];
  if (blockIdx.x == 0 && threadIdx.x == 0) rp[n] = etot;
}

// no atomic: slot comes from pir[] captured by the packed atomic
__global__ void fill_k(const int* __restrict__ ei, const float* __restrict__ w,
                       const float* __restrict__ dinv, const int* __restrict__ rp,
                       const int* __restrict__ pir, int2* __restrict__ epk, int E) {
  int e = blockIdx.x * TPB + threadIdx.x;
  if (e >= E) return;
  int s = ei[e];
  int d = ei[E + e];
  int pos = rp[d] + pir[e];
  float nrm = dinv[s] * w[e] * dinv[d];
  epk[pos] = make_int2(s, __float_as_int(nrm));
}

// ---------------- GEMM: H = act(X) @ W  (K=128 fixed), bf16 output ----------------

template<int COUT, bool RELU>
__global__ __launch_bounds__(256) void gemm_k(const float* __restrict__ X,
                                              const float* __restrict__ W,
                                              unsigned short* __restrict__ H, int n) {
  constexpr int CG   = COUT / 4;     // column groups (32 or 16)
  constexpr int RG   = 256 / CG;     // row groups   (8 or 16)
  constexpr int ROWS = RG * 4;       // rows/block   (32 or 64)
  __shared__ __align__(16) float Ws[64 * COUT];    // 32KB (128) / 16KB (64)
  __shared__ __align__(16) float Xs[ROWS * 128];   // 16KB (128) / 32KB (64)

  const int tid = threadIdx.x;
  const int r0  = blockIdx.x * ROWS;

  // stage X tile once (apply ReLU on load if requested)
  const int nrow = min(ROWS, n - r0);
  const float4* X4  = (const float4*)(X + (size_t)r0 * 128);
  float4*       Xs4 = (float4*)Xs;
  for (int i = tid; i < nrow * 32; i += 256) {
    float4 v = X4[i];
    if (RELU) {
      v.x = fmaxf(v.x, 0.f); v.y = fmaxf(v.y, 0.f);
      v.z = fmaxf(v.z, 0.f); v.w = fmaxf(v.w, 0.f);
    }
    Xs4[i] = v;
  }

  const int cg   = tid % CG;
  const int rg   = tid / CG;
  const int col0 = cg * 4;
  const int rb   = rg * 4;

  float4 acc[4];
  #pragma unroll
  for (int r = 0; r < 4; r++) acc[r] = make_float4(0.f, 0.f, 0.f, 0.f);

  for (int kb = 0; kb < 128; kb += 64) {
    __syncthreads();   // protects Ws reuse (and X staging on first pass)
    const float4* W4  = (const float4*)(W + (size_t)kb * COUT);
    float4*       Ws4 = (float4*)Ws;
    #pragma unroll
    for (int i = tid; i < 64 * COUT / 4; i += 256) Ws4[i] = W4[i];
    __syncthreads();

    #pragma unroll
    for (int k = 0; k < 64; k += 4) {
      float4 w0 = *(const float4*)&Ws[(k + 0) * COUT + col0];
      float4 w1 = *(const float4*)&Ws[(k + 1) * COUT + col0];
      float4 w2 = *(const float4*)&Ws[(k + 2) * COUT + col0];
      float4 w3 = *(const float4*)&Ws[(k + 3) * COUT + col0];
      #pragma unroll
      for (int r = 0; r < 4; r++) {
        float4 xv = *(const float4*)&Xs[(rb + r) * 128 + kb + k];
        acc[r].x += xv.x * w0.x + xv.y * w1.x + xv.z * w2.x + xv.w * w3.x;
        acc[r].y += xv.x * w0.y + xv.y * w1.y + xv.z * w2.y + xv.w * w3.y;
        acc[r].z += xv.x * w0.z + xv.y * w1.z + xv.z * w2.z + xv.w * w3.z;
        acc[r].w += xv.x * w0.w + xv.y * w1.w + xv.z * w2.w + xv.w * w3.w;
      }
    }
  }

  #pragma unroll
  for (int r = 0; r < 4; r++) {
    int row = r0 + rb + r;
    if (row < n) {
      ushort4 o;
      o.x = f2bf(acc[r].x);
      o.y = f2bf(acc[r].y);
      o.z = f2bf(acc[r].z);
      o.w = f2bf(acc[r].w);
      *(ushort4*)&H[(size_t)row * COUT + col0] = o;
    }
  }
}

// ---------------- aggregation: one wave per node, CSR gather (bf16 table) ----------
// out[j][c] = b[c] + dinv[j]^2 * h[j][c] + sum_e norm_e * h[col_e][c]

__global__ __launch_bounds__(256) void agg128(const unsigned short* __restrict__ H,
                                              const int* __restrict__ rp,
                                              const int2* __restrict__ epk,
                                              const float* __restrict__ dinv,
                                              const float* __restrict__ bias,
                                              float* __restrict__ OUT, int n) {
  int wid  = __builtin_amdgcn_readfirstlane(blockIdx.x * 4 + (threadIdx.x >> 6));
  int lane = threadIdx.x & 63;
  if (wid >= n) return;
  float di = dinv[wid];
  float w0 = di * di;
  unsigned hv = ((const unsigned*)(H + (size_t)wid * 128))[lane];
  float2 bv = ((const float2*)bias)[lane];
  float ax = bv.x + w0 * bf_lo(hv);
  float ay = bv.y + w0 * bf_hi(hv);
  int e  = rp[wid];
  int e1 = rp[wid + 1];
  for (; e + 7 < e1; e += 8) {
    int2 p[8];
    #pragma unroll
    for (int u = 0; u < 8; u++) p[u] = epk[e + u];
    unsigned h[8];
    #pragma unroll
    for (int u = 0; u < 8; u++) h[u] = ((const unsigned*)(H + (size_t)p[u].x * 128))[lane];
    #pragma unroll
    for (int u = 0; u < 8; u++) {
      float nw = __int_as_float(p[u].y);
      ax += nw * bf_lo(h[u]);
      ay += nw * bf_hi(h[u]);
    }
  }
  for (; e < e1; e++) {
    int2 p = epk[e];
    unsigned h = ((const unsigned*)(H + (size_t)p.x * 128))[lane];
    float nw = __int_as_float(p.y);
    ax += nw * bf_lo(h); ay += nw * bf_hi(h);
  }
  ((float2*)(OUT + (size_t)wid * 128))[lane] = make_float2(ax, ay);
}

__global__ __launch_bounds__(256) void agg64(const unsigned short* __restrict__ H,
                                             const int* __restrict__ rp,
                                             const int2* __restrict__ epk,
                                             const float* __restrict__ dinv,
                                             const float* __restrict__ bias,
                                             float* __restrict__ OUT, int n) {
  int wid  = __builtin_amdgcn_readfirstlane(blockIdx.x * 4 + (threadIdx.x >> 6));
  int lane = threadIdx.x & 63;
  if (wid >= n) return;
  float di = dinv[wid];
  float w0 = di * di;
  float hv = __uint_as_float(((unsigned)H[(size_t)wid * 64 + lane]) << 16);
  float acc = bias[lane] + w0 * hv;
  int e  = rp[wid];
  int e1 = rp[wid + 1];
  for (; e + 7 < e1; e += 8) {
    int2 p[8];
    #pragma unroll
    for (int u = 0; u < 8; u++) p[u] = epk[e + u];
    float h[8];
    #pragma unroll
    for (int u = 0; u < 8; u++)
      h[u] = __uint_as_float(((unsigned)H[(size_t)p[u].x * 64 + lane]) << 16);
    #pragma unroll
    for (int u = 0; u < 8; u++) acc += __int_as_float(p[u].y) * h[u];
  }
  for (; e < e1; e++) {
    int2 p = epk[e];
    float h = __uint_as_float(((unsigned)H[(size_t)p.x * 64 + lane]) << 16);
    acc += __int_as_float(p.y) * h;
  }
  OUT[(size_t)wid * 64 + lane] = acc;
}

// ---------------- launch ----------------

extern "C" void kernel_launch(void* const* d_in, const int* in_sizes, int n_in,
                              void* d_out, int out_size, void* d_ws, size_t ws_size,
                              hipStream_t stream) {
  const float* x  = (const float*)d_in[0];
  const int*   ei = (const int*)d_in[1];    // int64 in reference -> int32 on device
  const float* ew = (const float*)d_in[2];
  const float* W1 = (const float*)d_in[3];
  const float* b1 = (const float*)d_in[4];
  const float* W2 = (const float*)d_in[5];
  const float* b2 = (const float*)d_in[6];
  const float* W3 = (const float*)d_in[7];
  const float* b3 = (const float*)d_in[8];

  const int N = in_sizes[0] / 128;
  const int E = in_sizes[2];

  char* p = (char*)d_ws;
  auto carve = [&](size_t bytes) -> void* {
    void* r = (void*)p;
    p += (bytes + 255) & ~(size_t)255;
    return r;
  };
  unsigned long long* pk = (unsigned long long*)carve((size_t)N * 8);
  float* dinv   = (float*)carve((size_t)N * 4);
  int*   cnt    = (int*)  carve((size_t)N * 4);
  int*   rp     = (int*)  carve((size_t)(N + 1) * 4);
  int*   bsum   = (int*)  carve(512 * 4);
  int*   pir    = (int*)  carve((size_t)E * 4);
  int2*  epk    = (int2*) carve((size_t)E * 8);
  unsigned short* hbuf = (unsigned short*)carve((size_t)N * 128 * 2);  // bf16 table
  float* abuf   = (float*)carve((size_t)N * 128 * 4);

  const int NB = (N + TPB - 1) / TPB;
  const int EB = (E + TPB - 1) / TPB;

  // graph preprocessing (once per call; reused by all 3 layers)
  init_k<<<NB, TPB, 0, stream>>>(pk, N);
  edges_k<<<EB, TPB, 0, stream>>>(ei, ew, pk, pir, E);
  unpack_k<<<NB, TPB, 0, stream>>>(pk, dinv, cnt, N);
  scan_a<<<NB, TPB, 0, stream>>>(cnt, rp, bsum, N);
  scan_b<<<1, 512, 0, stream>>>(bsum, NB);
  scan_c<<<NB, TPB, 0, stream>>>(rp, bsum, N, E);
  fill_k<<<EB, TPB, 0, stream>>>(ei, ew, dinv, rp, pir, epk, E);

  const int aggBlocks = (N + 3) / 4;   // one 64-lane wave per node, 4 waves/block

  // layer 1: h = x @ W1 (bf16) ; agg + b1 -> abuf fp32
  gemm_k<128, false><<<(N + 31) / 32, 256, 0, stream>>>(x, W1, hbuf, N);
  agg128<<<aggBlocks, 256, 0, stream>>>(hbuf, rp, epk, dinv, b1, abuf, N);

  // layer 2: h = relu(a1) @ W2 (bf16) ; agg + b2 -> abuf fp32
  gemm_k<128, true><<<(N + 31) / 32, 256, 0, stream>>>(abuf, W2, hbuf, N);
  agg128<<<aggBlocks, 256, 0, stream>>>(hbuf, rp, epk, dinv, b2, abuf, N);

  // layer 3: h = relu(a2) @ W3 (bf16) ; agg + b3 -> d_out fp32
  gemm_k<64, true><<<(N + 63) / 64, 256, 0, stream>>>(abuf, W3, hbuf, N);
  agg64<<<aggBlocks, 256, 0, stream>>>(hbuf, rp, epk, dinv, b3, (float*)d_out, N);
}

// Round 8
// 394.346 us; speedup vs baseline: 2.4760x; 1.1737x over previous
//
#include <hip/hip_runtime.h>
#include <cstdint>
#include <cstddef>

#define TPB 256

// fp32 -> bf16 (round to nearest even), as raw ushort
__device__ __forceinline__ unsigned short f2bf(float f) {
  unsigned u = __float_as_uint(f);
  u += 0x7fffu + ((u >> 16) & 1u);
  return (unsigned short)(u >> 16);
}
__device__ __forceinline__ float bf_lo(unsigned u) { return __uint_as_float(u << 16); }
__device__ __forceinline__ float bf_hi(unsigned u) { return __uint_as_float(u & 0xffff0000u); }

#define FIXP 262144.0f   // 2^18 fixed-point scale for weighted degree
#define LOWMASK 0xFFFFFFFFFFULL

typedef __attribute__((ext_vector_type(8))) short  short8v;   // 8 bf16 (4 VGPRs)
typedef __attribute__((ext_vector_type(4))) float  float4v;   // MFMA acc

// ---------------- preprocessing ----------------

__global__ void init_k(unsigned long long* __restrict__ pk, int n) {
  int i = blockIdx.x * TPB + threadIdx.x;
  if (i < n) pk[i] = 0ULL;
}

// ONE packed atomic per edge: count in high 24 bits, fixed-point weighted degree in
// low 40 bits. Returned old count field = this edge's slot within its CSR row.
__global__ void edges_k(const int* __restrict__ ei, const float* __restrict__ w,
                        unsigned long long* __restrict__ pk, int* __restrict__ pir, int E) {
  int e = blockIdx.x * TPB + threadIdx.x;
  if (e >= E) return;
  int d = ei[E + e];
  unsigned long long v = (1ULL << 40) | (unsigned long long)(w[e] * FIXP + 0.5f);
  unsigned long long old = atomicAdd(&pk[d], v);
  pir[e] = (int)(old >> 40);
}

__global__ void unpack_k(const unsigned long long* __restrict__ pk,
                         float* __restrict__ dinv, int* __restrict__ cnt, int n) {
  int i = blockIdx.x * TPB + threadIdx.x;
  if (i >= n) return;
  unsigned long long p = pk[i];
  float deg = 1.0f + (float)(p & LOWMASK) * (1.0f / FIXP);   // self-loop weight 1 => deg >= 1
  dinv[i] = rsqrtf(deg);
  cnt[i]  = (int)(p >> 40);
}

__global__ void scan_a(const int* __restrict__ cnt, int* __restrict__ rp,
                       int* __restrict__ bsum, int n) {
  __shared__ int s[TPB];
  int i = blockIdx.x * TPB + threadIdx.x;
  int v = (i < n) ? cnt[i] : 0;
  s[threadIdx.x] = v;
  __syncthreads();
  #pragma unroll
  for (int off = 1; off < TPB; off <<= 1) {
    int t = (threadIdx.x >= off) ? s[threadIdx.x - off] : 0;
    __syncthreads();
    s[threadIdx.x] += t;
    __syncthreads();
  }
  if (i < n) rp[i] = s[threadIdx.x] - v;            // exclusive within block
  if (threadIdx.x == TPB - 1) bsum[blockIdx.x] = s[TPB - 1];
}

__global__ void scan_b(int* __restrict__ bsum, int nb) {
  __shared__ int s[512];
  int v = (threadIdx.x < nb) ? bsum[threadIdx.x] : 0;
  s[threadIdx.x] = v;
  __syncthreads();
  #pragma unroll
  for (int off = 1; off < 512; off <<= 1) {
    int t = (threadIdx.x >= off) ? s[threadIdx.x - off] : 0;
    __syncthreads();
    s[threadIdx.x] += t;
    __syncthreads();
  }
  if (threadIdx.x < nb) bsum[threadIdx.x] = s[threadIdx.x] - v;  // exclusive block offsets
}

__global__ void scan_c(int* __restrict__ rp, const int* __restrict__ bsum, int n, int etot) {
  int i = blockIdx.x * TPB + threadIdx.x;
  if (i < n) rp[i] += bsum[blockIdx.x];
  if (blockIdx.x == 0 && threadIdx.x == 0) rp[n] = etot;
}

// no atomic: slot comes from pir[] captured by the packed atomic
__global__ void fill_k(const int* __restrict__ ei, const float* __restrict__ w,
                       const float* __restrict__ dinv, const int* __restrict__ rp,
                       const int* __restrict__ pir, int2* __restrict__ epk, int E) {
  int e = blockIdx.x * TPB + threadIdx.x;
  if (e >= E) return;
  int s = ei[e];
  int d = ei[E + e];
  int pos = rp[d] + pir[e];
  float nrm = dinv[s] * w[e] * dinv[d];
  epk[pos] = make_int2(s, __float_as_int(nrm));
}

// transpose + bf16-convert all three weight matrices: wtX[c][k] = W[k][c]
__global__ void wt_k(const float* __restrict__ W1, const float* __restrict__ W2,
                     const float* __restrict__ W3,
                     unsigned short* __restrict__ wt1, unsigned short* __restrict__ wt2,
                     unsigned short* __restrict__ wt3) {
  int t = blockIdx.x * TPB + threadIdx.x;
  if (t < 16384) {                  // W1 128x128
    int c = t >> 7, k = t & 127;
    wt1[t] = f2bf(W1[k * 128 + c]);
  } else if (t < 32768) {           // W2 128x128
    int u = t - 16384;
    int c = u >> 7, k = u & 127;
    wt2[u] = f2bf(W2[k * 128 + c]);
  } else if (t < 40960) {           // W3 128x64
    int u = t - 32768;
    int c = u >> 7, k = u & 127;
    wt3[u] = f2bf(W3[k * 64 + c]);
  }
}

// ---------------- GEMM via MFMA: H = bf16(act(X)) @ bf16(W), fp32 acc, bf16 out ----
// One wave per 16-row strip; A-frags converted on the fly from fp32 X;
// B-frags read directly from the L1/L2-resident transposed weights (Wt[c][k] bf16).
// mfma_f32_16x16x32_bf16: A row=lane&15, k=(lane>>4)*8+j ; B col=lane&15, same k ;
// D col=lane&15, row=(lane>>4)*4+reg   [verified m89 mapping]

template<int COUT, bool RELU>
__global__ __launch_bounds__(256) void gemm_mfma(const float* __restrict__ X,
                                                 const unsigned short* __restrict__ Wt,
                                                 unsigned short* __restrict__ H, int n) {
  const int lane = threadIdx.x & 63;
  const int wv   = threadIdx.x >> 6;             // 0..3
  const int r0   = (blockIdx.x * 4 + wv) * 16;   // wave's row strip
  if (r0 >= n) return;
  const int c16   = lane & 15;
  const int kb    = (lane >> 4) * 8;             // 0,8,16,24
  const int row_c = min(r0 + c16, n - 1);        // clamp OOB loads (D row r only uses A row r)

  // load + convert A fragments: a[kk] holds k = kk*32 + kb .. +7
  short8v a[4];
  const float* xrow = X + (size_t)row_c * 128;
  #pragma unroll
  for (int kk = 0; kk < 4; kk++) {
    float4 lo = *(const float4*)(xrow + kk * 32 + kb);
    float4 hi = *(const float4*)(xrow + kk * 32 + kb + 4);
    float v0 = lo.x, v1 = lo.y, v2 = lo.z, v3 = lo.w;
    float v4 = hi.x, v5 = hi.y, v6 = hi.z, v7 = hi.w;
    if (RELU) {
      v0 = fmaxf(v0, 0.f); v1 = fmaxf(v1, 0.f); v2 = fmaxf(v2, 0.f); v3 = fmaxf(v3, 0.f);
      v4 = fmaxf(v4, 0.f); v5 = fmaxf(v5, 0.f); v6 = fmaxf(v6, 0.f); v7 = fmaxf(v7, 0.f);
    }
    short8v t;
    t[0] = (short)f2bf(v0); t[1] = (short)f2bf(v1);
    t[2] = (short)f2bf(v2); t[3] = (short)f2bf(v3);
    t[4] = (short)f2bf(v4); t[5] = (short)f2bf(v5);
    t[6] = (short)f2bf(v6); t[7] = (short)f2bf(v7);
    a[kk] = t;
  }

  constexpr int CT = COUT / 16;
  const int orow = r0 + (lane >> 4) * 4;
  #pragma unroll
  for (int ct = 0; ct < CT; ct++) {
    float4v acc = {0.f, 0.f, 0.f, 0.f};
    const unsigned short* wrow = Wt + (size_t)(ct * 16 + c16) * 128 + kb;
    #pragma unroll
    for (int kk = 0; kk < 4; kk++) {
      short8v b = *(const short8v*)(wrow + kk * 32);
      acc = __builtin_amdgcn_mfma_f32_16x16x32_bf16(a[kk], b, acc, 0, 0, 0);
    }
    const int ocol = ct * 16 + c16;
    #pragma unroll
    for (int r = 0; r < 4; r++) {
      if (orow + r < n)
        H[(size_t)(orow + r) * COUT + ocol] = f2bf(acc[r]);
    }
  }
}

// ---------------- aggregation: one wave per node, CSR gather (bf16 table) ----------
// out[j][c] = b[c] + dinv[j]^2 * h[j][c] + sum_e norm_e * h[col_e][c]

__global__ __launch_bounds__(256) void agg128(const unsigned short* __restrict__ H,
                                              const int* __restrict__ rp,
                                              const int2* __restrict__ epk,
                                              const float* __restrict__ dinv,
                                              const float* __restrict__ bias,
                                              float* __restrict__ OUT, int n) {
  int wid  = __builtin_amdgcn_readfirstlane(blockIdx.x * 4 + (threadIdx.x >> 6));
  int lane = threadIdx.x & 63;
  if (wid >= n) return;
  float di = dinv[wid];
  float w0 = di * di;
  unsigned hv = ((const unsigned*)(H + (size_t)wid * 128))[lane];
  float2 bv = ((const float2*)bias)[lane];
  float ax = bv.x + w0 * bf_lo(hv);
  float ay = bv.y + w0 * bf_hi(hv);
  int e  = rp[wid];
  int e1 = rp[wid + 1];
  for (; e + 7 < e1; e += 8) {
    int2 p[8];
    #pragma unroll
    for (int u = 0; u < 8; u++) p[u] = epk[e + u];
    unsigned h[8];
    #pragma unroll
    for (int u = 0; u < 8; u++) h[u] = ((const unsigned*)(H + (size_t)p[u].x * 128))[lane];
    #pragma unroll
    for (int u = 0; u < 8; u++) {
      float nw = __int_as_float(p[u].y);
      ax += nw * bf_lo(h[u]);
      ay += nw * bf_hi(h[u]);
    }
  }
  for (; e < e1; e++) {
    int2 p = epk[e];
    unsigned h = ((const unsigned*)(H + (size_t)p.x * 128))[lane];
    float nw = __int_as_float(p.y);
    ax += nw * bf_lo(h); ay += nw * bf_hi(h);
  }
  ((float2*)(OUT + (size_t)wid * 128))[lane] = make_float2(ax, ay);
}

__global__ __launch_bounds__(256) void agg64(const unsigned short* __restrict__ H,
                                             const int* __restrict__ rp,
                                             const int2* __restrict__ epk,
                                             const float* __restrict__ dinv,
                                             const float* __restrict__ bias,
                                             float* __restrict__ OUT, int n) {
  int wid  = __builtin_amdgcn_readfirstlane(blockIdx.x * 4 + (threadIdx.x >> 6));
  int lane = threadIdx.x & 63;
  if (wid >= n) return;
  float di = dinv[wid];
  float w0 = di * di;
  float hv = __uint_as_float(((unsigned)H[(size_t)wid * 64 + lane]) << 16);
  float acc = bias[lane] + w0 * hv;
  int e  = rp[wid];
  int e1 = rp[wid + 1];
  for (; e + 7 < e1; e += 8) {
    int2 p[8];
    #pragma unroll
    for (int u = 0; u < 8; u++) p[u] = epk[e + u];
    float h[8];
    #pragma unroll
    for (int u = 0; u < 8; u++)
      h[u] = __uint_as_float(((unsigned)H[(size_t)p[u].x * 64 + lane]) << 16);
    #pragma unroll
    for (int u = 0; u < 8; u++) acc += __int_as_float(p[u].y) * h[u];
  }
  for (; e < e1; e++) {
    int2 p = epk[e];
    float h = __uint_as_float(((unsigned)H[(size_t)p.x * 64 + lane]) << 16);
    acc += __int_as_float(p.y) * h;
  }
  OUT[(size_t)wid * 64 + lane] = acc;
}

// ---------------- launch ----------------

extern "C" void kernel_launch(void* const* d_in, const int* in_sizes, int n_in,
                              void* d_out, int out_size, void* d_ws, size_t ws_size,
                              hipStream_t stream) {
  const float* x  = (const float*)d_in[0];
  const int*   ei = (const int*)d_in[1];    // int64 in reference -> int32 on device
  const float* ew = (const float*)d_in[2];
  const float* W1 = (const float*)d_in[3];
  const float* b1 = (const float*)d_in[4];
  const float* W2 = (const float*)d_in[5];
  const float* b2 = (const float*)d_in[6];
  const float* W3 = (const float*)d_in[7];
  const float* b3 = (const float*)d_in[8];

  const int N = in_sizes[0] / 128;
  const int E = in_sizes[2];

  char* p = (char*)d_ws;
  auto carve = [&](size_t bytes) -> void* {
    void* r = (void*)p;
    p += (bytes + 255) & ~(size_t)255;
    return r;
  };
  unsigned long long* pk = (unsigned long long*)carve((size_t)N * 8);
  float* dinv   = (float*)carve((size_t)N * 4);
  int*   cnt    = (int*)  carve((size_t)N * 4);
  int*   rp     = (int*)  carve((size_t)(N + 1) * 4);
  int*   bsum   = (int*)  carve(512 * 4);
  int*   pir    = (int*)  carve((size_t)E * 4);
  int2*  epk    = (int2*) carve((size_t)E * 8);
  unsigned short* hbuf = (unsigned short*)carve((size_t)N * 128 * 2);  // bf16 table
  float* abuf   = (float*)carve((size_t)N * 128 * 4);
  unsigned short* wt1 = (unsigned short*)carve(16384 * 2);
  unsigned short* wt2 = (unsigned short*)carve(16384 * 2);
  unsigned short* wt3 = (unsigned short*)carve(8192 * 2);

  const int NB = (N + TPB - 1) / TPB;
  const int EB = (E + TPB - 1) / TPB;

  // graph preprocessing + weight transpose (once per call; reused by all 3 layers)
  init_k<<<NB, TPB, 0, stream>>>(pk, N);
  edges_k<<<EB, TPB, 0, stream>>>(ei, ew, pk, pir, E);
  unpack_k<<<NB, TPB, 0, stream>>>(pk, dinv, cnt, N);
  scan_a<<<NB, TPB, 0, stream>>>(cnt, rp, bsum, N);
  scan_b<<<1, 512, 0, stream>>>(bsum, NB);
  scan_c<<<NB, TPB, 0, stream>>>(rp, bsum, N, E);
  fill_k<<<EB, TPB, 0, stream>>>(ei, ew, dinv, rp, pir, epk, E);
  wt_k<<<160, TPB, 0, stream>>>(W1, W2, W3, wt1, wt2, wt3);

  const int aggBlocks  = (N + 3) / 4;        // one 64-lane wave per node
  const int gemmBlocks = (N + 63) / 64;      // 4 waves x 16 rows per block

  // layer 1: h = x @ W1 (bf16 mfma) ; agg + b1 -> abuf fp32
  gemm_mfma<128, false><<<gemmBlocks, 256, 0, stream>>>(x, wt1, hbuf, N);
  agg128<<<aggBlocks, 256, 0, stream>>>(hbuf, rp, epk, dinv, b1, abuf, N);

  // layer 2: h = relu(a1) @ W2 ; agg + b2 -> abuf fp32
  gemm_mfma<128, true><<<gemmBlocks, 256, 0, stream>>>(abuf, wt2, hbuf, N);
  agg128<<<aggBlocks, 256, 0, stream>>>(hbuf, rp, epk, dinv, b2, abuf, N);

  // layer 3: h = relu(a2) @ W3 ; agg + b3 -> d_out fp32
  gemm_mfma<64, true><<<gemmBlocks, 256, 0, stream>>>(abuf, wt3, hbuf, N);
  agg64<<<aggBlocks, 256, 0, stream>>>(hbuf, rp, epk, dinv, b3, (float*)d_out, N);
}